// Round 7
// baseline (80.668 us; speedup 1.0000x reference)
//
#include <hip/hip_runtime.h>
#include <math.h>

#define HW 1024
#define NB 16
#define TMAXS 1024

typedef unsigned long long ull;

__device__ __forceinline__ double u2d(ull u) {
  return __longlong_as_double((long long)u);
}
__device__ __forceinline__ ull d2u(double d) {
  return (ull)__double_as_longlong(d);
}

// key = exp(-(0.5*g + 0.5*h)/sqrt(32)) with pre-halved operands (validated
// bit-exact vs reference rounds 0-6: same f32 op chain, contract off).
__device__ __forceinline__ float keyhalf(float gh, float hh) {
#pragma clang fp contract(off)
  const float INV = 0.17677669529663687f; // fl32(1/sqrt(32))
  return expf(-(gh + hh) * INV);
}

// One DPP reduction stage on a packed value (nonnegative as f64; disabled
// source lanes contribute 0.0 = identity). Chain validated all rounds.
template <int CTRL>
__device__ __forceinline__ double dpp_fmax64(double x) {
  ull u = d2u(x);
  int lo = (int)(unsigned)u;
  int hi = (int)(unsigned)(u >> 32);
  int lo2 = __builtin_amdgcn_update_dpp(0, lo, CTRL, 0xF, 0xF, false);
  int hi2 = __builtin_amdgcn_update_dpp(0, hi, CTRL, 0xF, 0xF, false);
  double y = u2d(((ull)(unsigned)hi2 << 32) | (unsigned)lo2);
  return fmax(x, y);
}

__device__ __forceinline__ ull rdl64(double d, int l) {
  ull u = d2u(d);
  int lo = __builtin_amdgcn_readlane((int)(unsigned)u, l);
  int hi = __builtin_amdgcn_readlane((int)(unsigned)(u >> 32), l);
  return ((ull)(unsigned)hi << 32) | (unsigned)lo;
}

__device__ __forceinline__ int dlt_of(int idx) {
  const int k = (idx < 4) ? idx : idx + 1; // skip center
  return (k / 3 - 1) * 32 + (k % 3 - 1);
}

// SALU neighbor-validity mask. lanes: 0,1,2 = top row; 0,3,5 = left col;
// 2,4,7 = right col; 5,6,7 = bottom row.
__device__ __forceinline__ unsigned vmask_of(int cell) {
  unsigned m = 0xFFu;
  const int r = cell >> 5, c = cell & 31;
  if (r == 0) m &= ~0x07u;
  if (r == 31) m &= ~0xE0u;
  if (c == 0) m &= ~0x29u;
  if (c == 31) m &= ~0x94u;
  return m;
}

// ---------------------------------------------------------------------------
// Fused per-batch A* + backtrack, one wave per batch.
// R7 = R6 structure + EXP HOISTED OFF THE CRITICAL PATH (pkeys table).
//
// Identity: the key used when popping cell p to relax its neighbor j is
//   exp(-(0.5f*(g[p]+cm[p]) + hw[p+dlt_j]) * INV)
// whose operands are all fixed at the RELAX time of p (g[p] is the wave-
// uniform g2full written then; cm/hw static).  So at relax time, all 64
// lanes precompute the (<=8 relaxed cells) x (8 directions) future keys
// (ONE wave v_exp — same instruction cost as the old 8-lane exp) into
// pkeys[1024][8] (32 KB LDS).  At pop, lane j reads pkeys[sel*8+j] — the
// address depends only on sel, so it issues with the other HEAD reads —
// and packs pk = (bits<<32)|(1023-n).  No exp between read-return and the
// selection merge.
//
// Bit-exactness: precompute chain s=g_new+cm; gh=0.5f*s; exp(-(gh+hw)*INV)
// is operand-identical to the validated pop chain (g_new == stored g2full).
// Hazards: pop of p always follows its last relax; start's 8 slots are
// exact-initialized (g=0 path: s = 0.0f + cm, same add); pkeys zeroed for
// determinism; relax writes precede next-iter head reads in the in-order
// DS pipe; n != sel so no intra-iter alias; popped cells never re-relaxed
// (validated flag logic).  Argmax decomposition (chains A/C pre-merge,
// chain B 3-stage post) unchanged from R6 => bit-identical trajectory.
// ---------------------------------------------------------------------------
extern "C" __global__ void __launch_bounds__(64) astar_fused(
    const float* __restrict__ cm_g, const float* __restrict__ sm_g,
    const float* __restrict__ gm_g, const float* __restrict__ om_g,
    float* __restrict__ out) {
#pragma clang fp contract(off)
  const int b = blockIdx.x;
  const int lane = threadIdx.x;

  __shared__ __align__(16) uint4 cellT[HW];     // {g, cm, hw, flg}
  __shared__ __align__(16) ull key2[HW];        // (f32keybits | 1023-idx)
  __shared__ __align__(16) unsigned par[HW];    // parent | mark bit31
  __shared__ __align__(16) ull level1[64];      // per-16-cell-group max
  __shared__ __align__(16) unsigned pkeys[HW * 8]; // precomputed pop keys
  const float2* cell2 = (const float2*)cellT;   // {g, cm} pairs (stride 2)
  unsigned* cellu = (unsigned*)cellT;

  const float* cm = cm_g + b * HW;
  const float* sm = sm_g + b * HW;
  const float* gm = gm_g + b * HW;
  const float* om = om_g + b * HW;

  // ---- init pass 1: vectorized loads, locate goal/start ----
  float4 c4[4], o4[4];
  int gi = -1, si = -1;
#pragma unroll
  for (int q = 0; q < 4; ++q) {
    const int base = q * 256 + lane * 4;
    c4[q] = *(const float4*)(cm + base);
    o4[q] = *(const float4*)(om + base);
    const float4 s4 = *(const float4*)(sm + base);
    const float4 g4 = *(const float4*)(gm + base);
    const float sv[4] = {s4.x, s4.y, s4.z, s4.w};
    const float gv[4] = {g4.x, g4.y, g4.z, g4.w};
#pragma unroll
    for (int j = 0; j < 4; ++j) {
      if (gv[j] > 0.5f) gi = base + j;
      if (sv[j] > 0.5f) si = base + j;
    }
  }
#pragma unroll
  for (int m = 32; m >= 1; m >>= 1) {
    const int og = __shfl_xor(gi, m, 64);
    const int os = __shfl_xor(si, m, 64);
    gi = (og > gi) ? og : gi;
    si = (os > si) ? os : si;
  }
  const int goal = __builtin_amdgcn_readfirstlane(gi);
  const int start = __builtin_amdgcn_readfirstlane(si);

  // ---- init pass 2: h (exact ref op order), cell structs, key2, level1 ----
  level1[lane] = 0ull; // before the atomics below (same array: order kept)
#pragma unroll
  for (int q = 0; q < 32; ++q) { // zero pkeys (deterministic default)
    *(uint4*)&pkeys[q * 256 + lane * 4] = make_uint4(0u, 0u, 0u, 0u);
  }
  const float grf = (float)(goal >> 5), gcf = (float)(goal & 31);
#pragma unroll
  for (int q = 0; q < 4; ++q) {
    const int base = q * 256 + lane * 4;
    const float cv[4] = {c4[q].x, c4[q].y, c4[q].z, c4[q].w};
    const float ov[4] = {o4[q].x, o4[q].y, o4[q].z, o4[q].w};
    ull pk[4];
#pragma unroll
    for (int j = 0; j < 4; ++j) {
      const int cell = base + j;
      const float rr = (float)(cell >> 5), cc = (float)(cell & 31);
      const float dr = fabsf(rr - grf), dc = fabsf(cc - gcf);
      const float h0 = (dr + dc) - fminf(dr, dc); // exact (small ints)
      const float euc = sqrtf(dr * dr + dc * dc); // exact radicand
      const float t1 = 0.001f * euc;              // contract off: no fma
      const float hh = h0 + t1;
      const float hf = hh + cv[j]; // h_full (h + cm), exact ref order
      const float hw = 0.5f * hf;  // exact scaling
      unsigned fv = (ov[j] > 0.5f) ? 1u : 0u;
      pk[j] = (ull)(1023 - cell);
      if (cell == start) {
        fv |= 2u; // open = start map
        pk[j] = ((ull)__float_as_uint(keyhalf(0.0f, hw)) << 32) |
                (ull)(1023 - cell);
      }
      cellT[cell] = make_uint4(__float_as_uint(0.0f), __float_as_uint(cv[j]),
                               __float_as_uint(hw), fv);
      atomicMax(&level1[cell >> 4], pk[j]);
    }
    *(uint4*)&par[base] =
        make_uint4((unsigned)goal, (unsigned)goal, (unsigned)goal, (unsigned)goal);
    ulonglong2 k01, k23;
    k01.x = pk[0]; k01.y = pk[1];
    k23.x = pk[2]; k23.y = pk[3];
    *(ulonglong2*)&key2[base] = k01;
    *(ulonglong2*)&key2[base + 2] = k23;
  }
  __builtin_amdgcn_wave_barrier();

  // ---- init pass 2b: exact pop keys for START (g=0 path) ----
  {
    const float cs = __uint_as_float(cellu[4 * start + 1]); // cm[start]
    if (lane < 8) {
      const int m = (start + dlt_of(lane)) & 1023;
      const float hwm = __uint_as_float(cellu[4 * m + 2]);
      const float s0 = 0.0f + cs;   // same add as pop's sg.x + sg.y
      const float gh0 = 0.5f * s0;  // exact scaling
      const unsigned vm = vmask_of(start);
      if ((vm >> lane) & 1u)
        pkeys[start * 8 + lane] = __float_as_uint(keyhalf(gh0, hwm));
    }
  }
  __builtin_amdgcn_wave_barrier();
  ull stale = level1[lane]; // S_{-1} group maxes

  // loop-invariant lane decompositions
  const int dltrl = dlt_of(lane & 7);  // relax direction of slot rl
  const int dltjj = dlt_of(lane >> 3); // future-key direction jj
  const int rl = lane & 7;

  int sel = start; // step-0 argmax: start is the only open cell
  bool reached = false;

#pragma unroll 1
  for (int step = 0; step < TMAXS; ++step) {
    if (sel == goal) { reached = true; break; }
    const int gp = sel >> 4;
    const unsigned vmask = vmask_of(sel);

    // -- issue all HEAD reads (all addresses depend only on sel) --
    const float2 sg = cell2[2 * sel]; // broadcast {g[sel], cm[sel]}
    const int n = sel + dltrl;        // lanes 0..7: relax target
    const bool relaxer = (lane < 8) && ((vmask >> lane) & 1u);
    uint4 nv = make_uint4(0u, 0u, 0u, 0u);
    if (relaxer) nv = cellT[n];
    unsigned pkb = 0u;
    if (lane < 8) pkb = pkeys[sel * 8 + lane]; // precomputed pop key
    const bool gcl = (lane >= 16) && (lane < 32);
    const int gcell = gp * 16 + (lane - 16);
    ull gco = 0ull;
    if (gcl) gco = key2[gcell];
    // future-key source reads (late consumers; static fields)
    const int nrlc = (sel + dltrl) & 1023;
    const int mfk = (nrlc + dltjj) & 1023;
    const float cm8 = __uint_as_float(cellu[4 * nrlc + 1]);
    const float hw8 = __uint_as_float(cellu[4 * mfk + 2]);

    // -- chain A: 6-stage fold over stale' (register-only; hides under the
    //    LDS latency window) --
    double ma = (lane == gp) ? 0.0 : u2d(stale);
    ma = dpp_fmax64<0x111>(ma); // row_shr:1
    ma = dpp_fmax64<0x112>(ma); // row_shr:2
    ma = dpp_fmax64<0x114>(ma); // row_shr:4
    ma = dpp_fmax64<0x118>(ma); // row_shr:8
    ma = dpp_fmax64<0x142>(ma); // row_bcast:15
    ma = dpp_fmax64<0x143>(ma); // row_bcast:31 -> lane63 = max(all)

    // -- relax predicate + early cellT/par writes --
    const float g2full = sg.x + sg.y;  // g[sel] + cm[sel], exact ref order
    const unsigned f = nv.w;
    const bool updv =
        relaxer && (f & 1u) &&
        (((f & 6u) == 0u) || (((f & 2u) != 0u) && (__uint_as_float(nv.x) > g2full)));
    if (updv) {
      cellT[n] = make_uint4(__float_as_uint(g2full), nv.y, nv.z, f | 2u);
      par[n] = (unsigned)sel;
    }
    if (lane == 8) {
      cellu[4 * sel + 3] = 5u;          // pop: free|hist (validated const)
      key2[sel] = (ull)(1023 - sel);    // denormal entry
    }

    // -- chain C: 4-stage fold over patched group keys --
    ull gcp = gco;
    if (gcl && gcell == sel) gcp = (ull)(1023 - sel); // patch the pop
    double mc = gcl ? u2d(gcp) : 0.0;
    mc = dpp_fmax64<0x111>(mc); // row_shr:1
    mc = dpp_fmax64<0x112>(mc); // row_shr:2
    mc = dpp_fmax64<0x114>(mc); // row_shr:4
    mc = dpp_fmax64<0x118>(mc); // row_shr:8 -> lane31 = group max
    if (lane == 31) level1[gp] = d2u(mc); // rebuilt group max (single store)

    // -- merge of the non-fresh side --
    const ull GC = rdl64(mc, 31);
    const ull MA = rdl64(ma, 63);
    const ull MACv = (GC > MA) ? GC : MA;

    // -- fresh pk from PRECOMPUTED key bits (no exp in this chain) --
    ull pk = 0ull;
    if (updv) pk = ((ull)pkb << 32) | (ull)(1023 - n);
    if (updv) key2[n] = pk;
    if (updv) atomicMax(&level1[n >> 4], pk);
    const ull stale_n = level1[lane]; // after ALL level1 updates (in-order)

    // -- chain B: 3-stage fold over fresh pk (lanes 0..7) -> lane7 --
    double mb = updv ? u2d(pk) : 0.0;
    mb = dpp_fmax64<0x111>(mb); // row_shr:1
    mb = dpp_fmax64<0x112>(mb); // row_shr:2
    mb = dpp_fmax64<0x114>(mb); // row_shr:4 -> lane7 = max(lanes 0..7)
    const ull PB = rdl64(mb, 7);

    // -- final: one compare (u64 order == nonneg-f64 order, same ties) --
    const ull M = (PB > MACv) ? PB : MACv;
    const int nsel = 1023 - (int)((unsigned)M & 1023u);

    // -- future keys for cells relaxed THIS iter (consumed >= next iter;
    //    writes precede next head reads in the in-order DS pipe).
    //    new g of n_rl == wave-uniform g2full; cm/hw static fields. --
    const ull bal = __ballot(updv);
    if ((bal >> rl) & 1ull) {
      const float sfk = g2full + cm8;  // same add as pop's sg.x + sg.y
      const float ghfk = 0.5f * sfk;   // exact scaling
      pkeys[nrlc * 8 + (lane >> 3)] = __float_as_uint(keyhalf(ghfk, hw8));
    }

    sel = nsel;
    stale = stale_n;
    __builtin_amdgcn_wave_barrier();
  }
  if (reached && lane == 0) cellu[4 * goal + 3] |= 4u; // hist includes goal
  __builtin_amdgcn_wave_barrier();

  // ---- fused backtrack (lane 0): mark path via par bit31 ----
  if (lane == 0) {
    const unsigned pv = par[goal];
    par[goal] = pv | 0x80000000u; // path starts as goal one-hot
    unsigned loc = pv & 1023u;
#pragma unroll 1
    for (int i = 0; i < HW; ++i) {
      const unsigned w = par[loc];
      if (w & 0x80000000u) break; // deterministic replay of marked cells
      par[loc] = w | 0x80000000u;
      loc = w & 1023u;
    }
  }
  __builtin_amdgcn_wave_barrier();

  // ---- epilogue: hist + path ----
#pragma unroll
  for (int q = 0; q < 4; ++q) {
    const int base = q * 256 + lane * 4;
    float4 hv, pv;
    hv.x = (cellu[4 * (base + 0) + 3] & 4u) ? 1.0f : 0.0f;
    hv.y = (cellu[4 * (base + 1) + 3] & 4u) ? 1.0f : 0.0f;
    hv.z = (cellu[4 * (base + 2) + 3] & 4u) ? 1.0f : 0.0f;
    hv.w = (cellu[4 * (base + 3) + 3] & 4u) ? 1.0f : 0.0f;
    pv.x = (par[base + 0] >> 31) ? 1.0f : 0.0f;
    pv.y = (par[base + 1] >> 31) ? 1.0f : 0.0f;
    pv.z = (par[base + 2] >> 31) ? 1.0f : 0.0f;
    pv.w = (par[base + 3] >> 31) ? 1.0f : 0.0f;
    *(float4*)(out + b * HW + base) = hv;
    *(float4*)(out + NB * HW + b * HW + base) = pv;
  }
}

extern "C" void kernel_launch(void* const* d_in, const int* in_sizes, int n_in,
                              void* d_out, int out_size, void* d_ws,
                              size_t ws_size, hipStream_t stream) {
  const float* cm = (const float*)d_in[0];
  const float* sm = (const float*)d_in[1];
  const float* gm = (const float*)d_in[2];
  const float* om = (const float*)d_in[3];
  float* out = (float*)d_out;
  hipLaunchKernelGGL(astar_fused, dim3(NB), dim3(64), 0, stream, cm, sm, gm,
                     om, out);
}

// Round 8
// 78.310 us; speedup vs baseline: 1.0301x; 1.0301x over previous
//
#include <hip/hip_runtime.h>
#include <math.h>

#define HW 1024
#define NB 16
#define TMAXS 1024

typedef unsigned long long ull;

__device__ __forceinline__ double u2d(ull u) {
  return __longlong_as_double((long long)u);
}
__device__ __forceinline__ ull d2u(double d) {
  return (ull)__double_as_longlong(d);
}

// key = exp(-(0.5*g + 0.5*h)/sqrt(32)) with pre-halved operands (validated
// bit-exact vs reference rounds 0-7: same f32 op chain, contract off).
__device__ __forceinline__ float keyhalf(float gh, float hh) {
#pragma clang fp contract(off)
  const float INV = 0.17677669529663687f; // fl32(1/sqrt(32))
  return expf(-(gh + hh) * INV);
}

// (f32 key bits : 32 | (1023-idx) : 10) as u64 — order & ties bit-identical
// to the validated f64 packing; reinterpreted as f64 it is nonneg/non-NaN
// (key in [0,1] -> exp field <= 0x3F8), so the fmax DPP chain applies.
__device__ __forceinline__ ull packkey(float keyf, int idx) {
  return ((ull)__float_as_uint(keyf) << 32) | (ull)(1023 - idx);
}

// One DPP reduction stage on a packed value (nonnegative as f64; disabled
// source lanes contribute 0.0 = identity). Chain validated all rounds.
template <int CTRL>
__device__ __forceinline__ double dpp_fmax64(double x) {
  ull u = d2u(x);
  int lo = (int)(unsigned)u;
  int hi = (int)(unsigned)(u >> 32);
  int lo2 = __builtin_amdgcn_update_dpp(0, lo, CTRL, 0xF, 0xF, false);
  int hi2 = __builtin_amdgcn_update_dpp(0, hi, CTRL, 0xF, 0xF, false);
  double y = u2d(((ull)(unsigned)hi2 << 32) | (unsigned)lo2);
  return fmax(x, y);
}

__device__ __forceinline__ ull rdl64(double d, int l) {
  ull u = d2u(d);
  int lo = __builtin_amdgcn_readlane((int)(unsigned)u, l);
  int hi = __builtin_amdgcn_readlane((int)(unsigned)(u >> 32), l);
  return ((ull)(unsigned)hi << 32) | (unsigned)lo;
}

// ---------------------------------------------------------------------------
// Fused per-batch A* + backtrack, one wave per batch.
// FINAL = R4, the best-measured kernel (76.49 µs total, astar ~37 µs):
// split-argmax restructure over the incremental hierarchical argmax.
//   chain A (6-stage DPP) over register stale' (gp excluded)   — hides
//           under the LDS read latency window
//   chains B,C: fresh pk on lanes 0..7, patched group keys on lanes 16..31,
//           ONE shared 4-stage row fold (DPP rows don't leak) -> lane15 =
//           max pk, lane31 = max gc; lane31's value is the rebuilt group
//           max, stored directly to level1[gp] (replaces zero+16 atomics)
//   final: 6 readlanes + scalar u64 max3 (u64 order == nonneg-f64 order,
//           idx bits break ties) -> sel
// DS diet (validated bit-exact): cell struct uint4 {g, cm, hw, flg} = one
// b128 neighbor read + one b128 relax write; pop reads b64 {g, cm} and
// recomputes g2full = g+cm (same operands/op as ref); pop flag = const 5.
// DS order per iter: reads -> writes(cellT/par/key2) -> level1 store ->
// relax atomicMax -> stale read (same-array program order = hazard rules
// validated rounds 0-4).
//
// Post-R4 structural attempts, all REFUTED on hardware (kept for the
// record): R5 next-sel speculation (−15 µs: prefetch addresses resolve too
// late, added ~40 in-order DS ops/iter); R6 B/C fold split with pre-exp
// merge (neutral/−2 µs: fold tail not dominant); R7 exp-hoist via pkeys
// table (−4 µs: +4 DS ops/iter cost more than the exp latency saved).
// The loop is latency-bound (VALUBusy ~0.22%) with an irreducible serial
// chain: LDS round-trip (~120 cy) + relax/key/fold tail (~80 cy) per pop.
// ---------------------------------------------------------------------------
extern "C" __global__ void __launch_bounds__(64) astar_fused(
    const float* __restrict__ cm_g, const float* __restrict__ sm_g,
    const float* __restrict__ gm_g, const float* __restrict__ om_g,
    float* __restrict__ out) {
#pragma clang fp contract(off)
  const int b = blockIdx.x;
  const int lane = threadIdx.x;

  __shared__ __align__(16) uint4 cellT[HW];  // {g, cm, hw, flg}
  __shared__ __align__(16) ull key2[HW];     // packed (f32keybits | 1023-idx)
  __shared__ __align__(16) unsigned par[HW]; // parent | mark bit31
  __shared__ __align__(16) ull level1[64];   // per-16-cell-group max
  const float2* cell2 = (const float2*)cellT; // {g, cm} pairs (stride 2)
  unsigned* cellu = (unsigned*)cellT;

  const float* cm = cm_g + b * HW;
  const float* sm = sm_g + b * HW;
  const float* gm = gm_g + b * HW;
  const float* om = om_g + b * HW;

  // ---- init pass 1: vectorized loads, locate goal/start ----
  float4 c4[4], o4[4];
  int gi = -1, si = -1;
#pragma unroll
  for (int q = 0; q < 4; ++q) {
    const int base = q * 256 + lane * 4;
    c4[q] = *(const float4*)(cm + base);
    o4[q] = *(const float4*)(om + base);
    const float4 s4 = *(const float4*)(sm + base);
    const float4 g4 = *(const float4*)(gm + base);
    const float sv[4] = {s4.x, s4.y, s4.z, s4.w};
    const float gv[4] = {g4.x, g4.y, g4.z, g4.w};
#pragma unroll
    for (int j = 0; j < 4; ++j) {
      if (gv[j] > 0.5f) gi = base + j;
      if (sv[j] > 0.5f) si = base + j;
    }
  }
#pragma unroll
  for (int m = 32; m >= 1; m >>= 1) {
    const int og = __shfl_xor(gi, m, 64);
    const int os = __shfl_xor(si, m, 64);
    gi = (og > gi) ? og : gi;
    si = (os > si) ? os : si;
  }
  const int goal = __builtin_amdgcn_readfirstlane(gi);
  const int start = __builtin_amdgcn_readfirstlane(si);

  // ---- init pass 2: h (exact ref op order), cell structs, key2, level1 ----
  level1[lane] = 0ull; // before the atomics below (same array: order kept)
  const float grf = (float)(goal >> 5), gcf = (float)(goal & 31);
#pragma unroll
  for (int q = 0; q < 4; ++q) {
    const int base = q * 256 + lane * 4;
    const float cv[4] = {c4[q].x, c4[q].y, c4[q].z, c4[q].w};
    const float ov[4] = {o4[q].x, o4[q].y, o4[q].z, o4[q].w};
    ull pk[4];
#pragma unroll
    for (int j = 0; j < 4; ++j) {
      const int cell = base + j;
      const float rr = (float)(cell >> 5), cc = (float)(cell & 31);
      const float dr = fabsf(rr - grf), dc = fabsf(cc - gcf);
      const float h0 = (dr + dc) - fminf(dr, dc); // exact (small ints)
      const float euc = sqrtf(dr * dr + dc * dc); // exact radicand
      const float t1 = 0.001f * euc;              // contract off: no fma
      const float hh = h0 + t1;
      const float hf = hh + cv[j]; // h_full (h + cm), exact ref order
      const float hw = 0.5f * hf;  // exact scaling
      unsigned fv = (ov[j] > 0.5f) ? 1u : 0u;
      pk[j] = (ull)(1023 - cell);
      if (cell == start) {
        fv |= 2u; // open = start map
        pk[j] = packkey(keyhalf(0.0f, hw), cell);
      }
      cellT[cell] = make_uint4(__float_as_uint(0.0f), __float_as_uint(cv[j]),
                               __float_as_uint(hw), fv);
      atomicMax(&level1[cell >> 4], pk[j]);
    }
    *(uint4*)&par[base] =
        make_uint4((unsigned)goal, (unsigned)goal, (unsigned)goal, (unsigned)goal);
    ulonglong2 k01, k23;
    k01.x = pk[0]; k01.y = pk[1];
    k23.x = pk[2]; k23.y = pk[3];
    *(ulonglong2*)&key2[base] = k01;
    *(ulonglong2*)&key2[base + 2] = k23;
  }
  __builtin_amdgcn_wave_barrier();
  ull stale = level1[lane]; // S_{-1} group maxes

  int dlt = 0;
  if (lane < 8) {
    const int k = (lane < 4) ? lane : lane + 1; // skip center
    dlt = (k / 3 - 1) * 32 + (k % 3 - 1);
  }

  int sel = start; // step-0 argmax: start is the only open cell
  bool reached = false;

#pragma unroll 1
  for (int step = 0; step < TMAXS; ++step) {
    if (sel == goal) { reached = true; break; }
    const int gp = sel >> 4;

    // scalar (SALU) neighbor-validity mask on uniform sel
    // lanes: 0,1,2 = top row; 0,3,5 = left col; 2,4,7 = right col;
    //        5,6,7 = bottom row
    const int sr = sel >> 5, sc = sel & 31;
    unsigned vmask = 0xFFu;
    if (sr == 0) vmask &= ~0x07u;
    if (sr == 31) vmask &= ~0xE0u;
    if (sc == 0) vmask &= ~0x29u;
    if (sc == 31) vmask &= ~0x94u;

    // -- issue all LDS reads first --
    const float2 sg = cell2[2 * sel]; // broadcast {g[sel], cm[sel]}
    const int n = sel + dlt;
    const bool relaxer = (lane < 8) && ((vmask >> lane) & 1u);
    uint4 nv = make_uint4(0u, 0u, 0u, 0u);
    if (relaxer) nv = cellT[n];
    const bool gcl = (lane >= 16) && (lane < 32);
    const int gcell = gp * 16 + (lane - 16);
    ull gco = 0ull;
    if (gcl) gco = key2[gcell];

    // -- chain A: 6-stage fold over stale' (register-only; hides under the
    //    LDS latency window) --
    double ma = (lane == gp) ? 0.0 : u2d(stale);
    ma = dpp_fmax64<0x111>(ma); // row_shr:1
    ma = dpp_fmax64<0x112>(ma); // row_shr:2
    ma = dpp_fmax64<0x114>(ma); // row_shr:4
    ma = dpp_fmax64<0x118>(ma); // row_shr:8
    ma = dpp_fmax64<0x142>(ma); // row_bcast:15
    ma = dpp_fmax64<0x143>(ma); // row_bcast:31 -> lane63 = max(all)

    // -- relax predicate + early cellT/par writes (pre-exp) --
    const float g2full = sg.x + sg.y; // g[sel] + cm[sel], exact ref order
    const float g2h = 0.5f * g2full;  // exact scaling
    const unsigned f = nv.w;
    const bool updv =
        relaxer && (f & 1u) &&
        (((f & 6u) == 0u) || (((f & 2u) != 0u) && (__uint_as_float(nv.x) > g2full)));
    if (updv) {
      cellT[n] = make_uint4(__float_as_uint(g2full), nv.y, nv.z, f | 2u);
      par[n] = (unsigned)sel;
    }
    if (lane == 8) {
      cellu[4 * sel + 3] = 5u;       // pop: free|hist (validated const)
      key2[sel] = (ull)(1023 - sel); // denormal entry
    }

    // -- exp + pk + key2 write --
    ull pk = 0ull;
    if (updv) pk = packkey(keyhalf(g2h, __uint_as_float(nv.z)), n);
    if (updv) key2[n] = pk;

    // -- chains B,C: shared 4-stage row fold (rows don't leak) --
    ull gcp = gco;
    if (gcl && gcell == sel) gcp = (ull)(1023 - sel); // patch the pop
    double ml = 0.0;
    if (gcl) ml = u2d(gcp);
    if (updv) ml = u2d(pk);
    ml = dpp_fmax64<0x111>(ml); // row_shr:1
    ml = dpp_fmax64<0x112>(ml); // row_shr:2
    ml = dpp_fmax64<0x114>(ml); // row_shr:4
    ml = dpp_fmax64<0x118>(ml); // row_shr:8
    // lane15 = max pk (lanes 0..7), lane31 = max gcp (lanes 16..31)

    // -- level1 maintenance: rebuilt group max from the fold itself, then
    //    relax atomics, then stale snapshot (same-array order) --
    if (lane == 31) level1[gp] = d2u(ml);
    if (updv) atomicMax(&level1[n >> 4], pk);
    const ull stale_n = level1[lane];

    // -- readlanes + scalar u64 max3 (== nonneg-f64 order, same ties) --
    const ull B2 = rdl64(ml, 15);
    const ull C2 = rdl64(ml, 31);
    const ull A2 = rdl64(ma, 63);
    ull M = (B2 > C2) ? B2 : C2;
    M = (M > A2) ? M : A2;
    sel = 1023 - (int)((unsigned)M & 1023u);
    stale = stale_n;
    __builtin_amdgcn_wave_barrier();
  }
  if (reached && lane == 0) cellu[4 * goal + 3] |= 4u; // hist includes goal
  __builtin_amdgcn_wave_barrier();

  // ---- fused backtrack (lane 0): mark path via par bit31 ----
  if (lane == 0) {
    const unsigned pv = par[goal];
    par[goal] = pv | 0x80000000u; // path starts as goal one-hot
    unsigned loc = pv & 1023u;
#pragma unroll 1
    for (int i = 0; i < HW; ++i) {
      const unsigned w = par[loc];
      if (w & 0x80000000u) break; // deterministic replay of marked cells
      par[loc] = w | 0x80000000u;
      loc = w & 1023u;
    }
  }
  __builtin_amdgcn_wave_barrier();

  // ---- epilogue: hist + path ----
#pragma unroll
  for (int q = 0; q < 4; ++q) {
    const int base = q * 256 + lane * 4;
    float4 hv, pv;
    hv.x = (cellu[4 * (base + 0) + 3] & 4u) ? 1.0f : 0.0f;
    hv.y = (cellu[4 * (base + 1) + 3] & 4u) ? 1.0f : 0.0f;
    hv.z = (cellu[4 * (base + 2) + 3] & 4u) ? 1.0f : 0.0f;
    hv.w = (cellu[4 * (base + 3) + 3] & 4u) ? 1.0f : 0.0f;
    pv.x = (par[base + 0] >> 31) ? 1.0f : 0.0f;
    pv.y = (par[base + 1] >> 31) ? 1.0f : 0.0f;
    pv.z = (par[base + 2] >> 31) ? 1.0f : 0.0f;
    pv.w = (par[base + 3] >> 31) ? 1.0f : 0.0f;
    *(float4*)(out + b * HW + base) = hv;
    *(float4*)(out + NB * HW + b * HW + base) = pv;
  }
}

extern "C" void kernel_launch(void* const* d_in, const int* in_sizes, int n_in,
                              void* d_out, int out_size, void* d_ws,
                              size_t ws_size, hipStream_t stream) {
  const float* cm = (const float*)d_in[0];
  const float* sm = (const float*)d_in[1];
  const float* gm = (const float*)d_in[2];
  const float* om = (const float*)d_in[3];
  float* out = (float*)d_out;
  hipLaunchKernelGGL(astar_fused, dim3(NB), dim3(64), 0, stream, cm, sm, gm,
                     om, out);
}